// Round 3
// baseline (518.149 us; speedup 1.0000x reference)
//
#include <hip/hip_runtime.h>
#include <hip/hip_bf16.h>

// EdgeBlock: out[e] = (relu(relu(x@W0+b0)@W1+b1))@W2+b2, x = [edge|recv|send|glob] (64)
// bf16 hi/lo split MFMA (fp32-equivalent accuracy), transposed products so inter-layer
// data stays lane-local. R3: weights+biases LDS-resident (frees ~130 VGPR -> 12 waves/CU),
// cvt_pk pair-packed bf16 splits, split accumulator chains, persistent 768-block grid.

typedef float f32x4 __attribute__((ext_vector_type(4)));
typedef short short8 __attribute__((ext_vector_type(8)));
typedef unsigned int u32;
typedef unsigned int u32x4 __attribute__((ext_vector_type(4)));

__device__ __forceinline__ unsigned short f2bf(float f) {
    union { float f; u32 u; } v; v.f = f;
    u32 u = v.u;
    u += 0x7FFFu + ((u >> 16) & 1u);   // RNE
    return (unsigned short)(u >> 16);
}
__device__ __forceinline__ float bf2f(unsigned short b) {
    union { u32 u; float f; } v; v.u = ((u32)b) << 16;
    return v.f;
}
// packed pair: low half = bf16(a), high half = bf16(b)   (v_cvt_pk_bf16_f32)
__device__ __forceinline__ u32 pk2(float a, float b) {
    union { __hip_bfloat162 v; u32 u; } c;
    c.v = __float22bfloat162_rn(make_float2(a, b));
    return c.u;
}
__device__ __forceinline__ float lo_f(u32 p) { union { u32 u; float f; } c; c.u = p << 16; return c.f; }
__device__ __forceinline__ float hi_f(u32 p) { union { u32 u; float f; } c; c.u = p & 0xffff0000u; return c.f; }
// hi/lo split of 4 floats -> 2 packed-hi u32 + 2 packed-lo u32
__device__ __forceinline__ void split4(f32x4 v, u32& h0, u32& h1, u32& l0, u32& l1) {
    h0 = pk2(v[0], v[1]);
    h1 = pk2(v[2], v[3]);
    l0 = pk2(v[0] - lo_f(h0), v[1] - hi_f(h0));
    l1 = pk2(v[2] - lo_f(h1), v[3] - hi_f(h1));
}
__device__ __forceinline__ short8 s8(u32 a, u32 b, u32 c, u32 d) {
    union { u32x4 u; short8 s; } t; t.u = u32x4{a, b, c, d}; return t.s;
}

// ---------------- prep: pack weights/biases into MFMA fragment layout in ws -------------
// ws layout (ushort units):
//   w0h[4096] w0l[4096] w1h[4096] w1l[4096] w2h[1024] w2l[1024]   (frags: [f][lane][j])
// then (float units, byte 36864): b0f[4][64][4] b1f[4][64][4] b2f[64][4]   (total 46080 B)
__global__ void prep_kernel(const float* __restrict__ W0, const float* __restrict__ b0,
                            const float* __restrict__ W1, const float* __restrict__ b1,
                            const float* __restrict__ W2, const float* __restrict__ b2,
                            void* __restrict__ ws) {
    unsigned short* w0h = (unsigned short*)ws;
    unsigned short* w0l = w0h + 4096;
    unsigned short* w1h = w0h + 8192;
    unsigned short* w1l = w0h + 12288;
    unsigned short* w2h = w0h + 16384;
    unsigned short* w2l = w0h + 17408;
    float* b0f = (float*)(w0h + 18432);
    float* b1f = b0f + 1024;
    float* b2f = b0f + 2048;
    const int tid = blockIdx.x * blockDim.x + threadIdx.x;
    const int gstride = gridDim.x * blockDim.x;

    // W0 frags: A[m=hid][k=in] = W0[k][m]; k-slot map mu0 = 32*kt + 8*g + j
    for (int idx = tid; idx < 4096; idx += gstride) {
        int j = idx & 7, lane = (idx >> 3) & 63, f = idx >> 9;
        int t = f >> 1, kt = f & 1, mr = lane & 15, g = lane >> 4;
        float w = W0[(32 * kt + 8 * g + j) * 64 + (16 * t + mr)];
        unsigned short h = f2bf(w);
        w0h[idx] = h;
        w0l[idx] = f2bf(w - bf2f(h));
    }
    // W1 frags: k-slot map mu = 16*(2*kt + (j>>2)) + 4*g + (j&3)  (matches layer-0 output)
    for (int idx = tid; idx < 4096; idx += gstride) {
        int j = idx & 7, lane = (idx >> 3) & 63, f = idx >> 9;
        int t = f >> 1, kt = f & 1, mr = lane & 15, g = lane >> 4;
        int mu = 16 * (2 * kt + (j >> 2)) + 4 * g + (j & 3);
        float w = W1[mu * 64 + (16 * t + mr)];
        unsigned short h = f2bf(w);
        w1h[idx] = h;
        w1l[idx] = f2bf(w - bf2f(h));
    }
    // W2 frags: [2][64][8], same mu map, single M-tile
    for (int idx = tid; idx < 1024; idx += gstride) {
        int j = idx & 7, lane = (idx >> 3) & 63, kt = idx >> 9;
        int mr = lane & 15, g = lane >> 4;
        int mu = 16 * (2 * kt + (j >> 2)) + 4 * g + (j & 3);
        float w = W2[mu * 16 + mr];
        unsigned short h = f2bf(w);
        w2h[idx] = h;
        w2l[idx] = f2bf(w - bf2f(h));
    }
    // bias frags [t][lane][r]: lane holds units 16*t + 4*g + r
    for (int idx = tid; idx < 1024; idx += gstride) {
        int t = idx >> 8, lane = (idx >> 2) & 63, r = idx & 3;
        int g = lane >> 4;
        b0f[idx] = b0[16 * t + 4 * g + r];
        b1f[idx] = b1[16 * t + 4 * g + r];
    }
    for (int idx = tid; idx < 256; idx += gstride) {
        int lane = idx >> 2, r = idx & 3, g = lane >> 4;
        b2f[idx] = b2[4 * g + r];
    }
}

// ---------------- main kernel: one wave computes 16 edges per iteration ----------------
__global__ __launch_bounds__(256, 3) void edge_mlp_kernel(
    const float* __restrict__ edges, const float* __restrict__ nodes,
    const float* __restrict__ globals_, const int* __restrict__ senders,
    const int* __restrict__ receivers, const int* __restrict__ gids,
    const void* __restrict__ ws, float* __restrict__ out, int n_tiles, int iters) {

    __shared__ f32x4 smem4[2880];                 // 46080 B: weights + biases
    {   // stage ws -> LDS (one-time)
        const f32x4* src = (const f32x4*)ws;
        for (int i = threadIdx.x; i < 2880; i += 256) smem4[i] = src[i];
    }
    __syncthreads();

    const short8* w0h = (const short8*)smem4;             // [8][64] frags
    const short8* w0l = w0h + 512;
    const short8* w1h = w0h + 1024;
    const short8* w1l = w0h + 1536;
    const short8* w2h = w0h + 2048;                       // [2][64]
    const short8* w2l = w0h + 2176;
    const f32x4* b0v = smem4 + 2304;                      // [4][64]
    const f32x4* b1v = b0v + 256;
    const f32x4* b2v = b1v + 256;                         // [64]

    const int lane = threadIdx.x & 63;
    const int wv = threadIdx.x >> 6;
    const int mr = lane & 15;
    const int g = lane >> 4;

    const int W = gridDim.x << 2;                 // total waves
    const int wave_id = (blockIdx.x << 2) | wv;
    const int last = n_tiles - 1;
    #define TILE_OF(i) (((wave_id + (i) * W) < n_tiles) ? (wave_id + (i) * W) : last)

    // ---- pipeline prologue ----
    int e_cur = TILE_OF(0) * 16 + mr;
    int ri0 = receivers[e_cur], si0 = senders[e_cur], gi0 = gids[e_cur];
    const float* p0 = (g < 2) ? (edges + (size_t)e_cur * 16 + 8 * g)
                              : (nodes + (size_t)ri0 * 16 + 8 * (g - 2));
    const float* p1 = (g < 2) ? (nodes + (size_t)si0 * 16 + 8 * g)
                              : (globals_ + (size_t)gi0 * 16 + 8 * (g - 2));
    f32x4 x0 = *(const f32x4*)p0;
    f32x4 x1 = *(const f32x4*)(p0 + 4);
    f32x4 x2 = *(const f32x4*)p1;
    f32x4 x3 = *(const f32x4*)(p1 + 4);

    int e_nxt = TILE_OF(1) * 16 + mr;
    int ri_n = receivers[e_nxt], si_n = senders[e_nxt], gi_n = gids[e_nxt];

    for (int i = 0; i < iters; ++i) {
        // ---- prefetch data for iteration i+1 ----
        const float* q0 = (g < 2) ? (edges + (size_t)e_nxt * 16 + 8 * g)
                                  : (nodes + (size_t)ri_n * 16 + 8 * (g - 2));
        const float* q1 = (g < 2) ? (nodes + (size_t)si_n * 16 + 8 * g)
                                  : (globals_ + (size_t)gi_n * 16 + 8 * (g - 2));
        f32x4 n0 = *(const f32x4*)q0;
        f32x4 n1 = *(const f32x4*)(q0 + 4);
        f32x4 n2 = *(const f32x4*)q1;
        f32x4 n3 = *(const f32x4*)(q1 + 4);

        // ---- prefetch indices for iteration i+2 ----
        int e_nn = TILE_OF(i + 2) * 16 + mr;
        int ri_nn = receivers[e_nn], si_nn = senders[e_nn], gi_nn = gids[e_nn];

        // ---- split inputs (k-slot map mu0 = 32*kt + 8*g + j; pairs contiguous) ----
        u32 ah0, ah1, al0, al1, bh0, bh1, bl0, bl1;
        u32 ch0, ch1, cl0, cl1, dh0, dh1, dl0, dl1;
        split4(x0, ah0, ah1, al0, al1);
        split4(x1, bh0, bh1, bl0, bl1);
        split4(x2, ch0, ch1, cl0, cl1);
        split4(x3, dh0, dh1, dl0, dl1);
        short8 XH0 = s8(ah0, ah1, bh0, bh1), XL0 = s8(al0, al1, bl0, bl1);
        short8 XH1 = s8(ch0, ch1, dh0, dh1), XL1 = s8(cl0, cl1, dl0, dl1);

        // ---- layer 0 (hi/lo: Wl*Xh + Wh*Xl + Wh*Xh), bias in C-init, 2 acc chains ----
        u32 HHw[2][4], HLw[2][4];
#pragma unroll
        for (int t = 0; t < 4; ++t) {
            short8 Wh0 = w0h[(t * 2 + 0) * 64 + lane];
            short8 Wh1 = w0h[(t * 2 + 1) * 64 + lane];
            short8 Wl0 = w0l[(t * 2 + 0) * 64 + lane];
            short8 Wl1 = w0l[(t * 2 + 1) * 64 + lane];
            f32x4 p = b0v[t * 64 + lane];
            f32x4 q = {0.f, 0.f, 0.f, 0.f};
            p = __builtin_amdgcn_mfma_f32_16x16x32_bf16(Wl0, XH0, p, 0, 0, 0);
            q = __builtin_amdgcn_mfma_f32_16x16x32_bf16(Wl1, XH1, q, 0, 0, 0);
            p = __builtin_amdgcn_mfma_f32_16x16x32_bf16(Wh0, XL0, p, 0, 0, 0);
            q = __builtin_amdgcn_mfma_f32_16x16x32_bf16(Wh1, XL1, q, 0, 0, 0);
            p = __builtin_amdgcn_mfma_f32_16x16x32_bf16(Wh0, XH0, p, 0, 0, 0);
            q = __builtin_amdgcn_mfma_f32_16x16x32_bf16(Wh1, XH1, q, 0, 0, 0);
            f32x4 s = p + q;
            float v0 = fmaxf(s[0], 0.f), v1 = fmaxf(s[1], 0.f);
            float v2 = fmaxf(s[2], 0.f), v3 = fmaxf(s[3], 0.f);
            u32 h0 = pk2(v0, v1), h1 = pk2(v2, v3);
            u32 l0 = pk2(v0 - lo_f(h0), v1 - hi_f(h0));
            u32 l1 = pk2(v2 - lo_f(h1), v3 - hi_f(h1));
            int kt = t >> 1, sl = (t & 1) << 1;
            HHw[kt][sl] = h0; HHw[kt][sl + 1] = h1;
            HLw[kt][sl] = l0; HLw[kt][sl + 1] = l1;
        }
        short8 HH0 = s8(HHw[0][0], HHw[0][1], HHw[0][2], HHw[0][3]);
        short8 HH1 = s8(HHw[1][0], HHw[1][1], HHw[1][2], HHw[1][3]);
        short8 HL0 = s8(HLw[0][0], HLw[0][1], HLw[0][2], HLw[0][3]);
        short8 HL1 = s8(HLw[1][0], HLw[1][1], HLw[1][2], HLw[1][3]);

        // ---- layer 1 ----
        u32 GHw[2][4], GLw[2][4];
#pragma unroll
        for (int t = 0; t < 4; ++t) {
            short8 Wh0 = w1h[(t * 2 + 0) * 64 + lane];
            short8 Wh1 = w1h[(t * 2 + 1) * 64 + lane];
            short8 Wl0 = w1l[(t * 2 + 0) * 64 + lane];
            short8 Wl1 = w1l[(t * 2 + 1) * 64 + lane];
            f32x4 p = b1v[t * 64 + lane];
            f32x4 q = {0.f, 0.f, 0.f, 0.f};
            p = __builtin_amdgcn_mfma_f32_16x16x32_bf16(Wl0, HH0, p, 0, 0, 0);
            q = __builtin_amdgcn_mfma_f32_16x16x32_bf16(Wl1, HH1, q, 0, 0, 0);
            p = __builtin_amdgcn_mfma_f32_16x16x32_bf16(Wh0, HL0, p, 0, 0, 0);
            q = __builtin_amdgcn_mfma_f32_16x16x32_bf16(Wh1, HL1, q, 0, 0, 0);
            p = __builtin_amdgcn_mfma_f32_16x16x32_bf16(Wh0, HH0, p, 0, 0, 0);
            q = __builtin_amdgcn_mfma_f32_16x16x32_bf16(Wh1, HH1, q, 0, 0, 0);
            f32x4 s = p + q;
            float v0 = fmaxf(s[0], 0.f), v1 = fmaxf(s[1], 0.f);
            float v2 = fmaxf(s[2], 0.f), v3 = fmaxf(s[3], 0.f);
            u32 h0 = pk2(v0, v1), h1 = pk2(v2, v3);
            u32 l0 = pk2(v0 - lo_f(h0), v1 - hi_f(h0));
            u32 l1 = pk2(v2 - lo_f(h1), v3 - hi_f(h1));
            int kt = t >> 1, sl = (t & 1) << 1;
            GHw[kt][sl] = h0; GHw[kt][sl + 1] = h1;
            GLw[kt][sl] = l0; GLw[kt][sl + 1] = l1;
        }
        short8 GH0 = s8(GHw[0][0], GHw[0][1], GHw[0][2], GHw[0][3]);
        short8 GH1 = s8(GHw[1][0], GHw[1][1], GHw[1][2], GHw[1][3]);
        short8 GL0 = s8(GLw[0][0], GLw[0][1], GLw[0][2], GLw[0][3]);
        short8 GL1 = s8(GLw[1][0], GLw[1][1], GLw[1][2], GLw[1][3]);

        // ---- layer 2 (single M-tile) ----
        short8 Vh0 = w2h[lane], Vh1 = w2h[64 + lane];
        short8 Vl0 = w2l[lane], Vl1 = w2l[64 + lane];
        f32x4 p = b2v[lane];
        f32x4 q = {0.f, 0.f, 0.f, 0.f};
        p = __builtin_amdgcn_mfma_f32_16x16x32_bf16(Vl0, GH0, p, 0, 0, 0);
        q = __builtin_amdgcn_mfma_f32_16x16x32_bf16(Vl1, GH1, q, 0, 0, 0);
        p = __builtin_amdgcn_mfma_f32_16x16x32_bf16(Vh0, GL0, p, 0, 0, 0);
        q = __builtin_amdgcn_mfma_f32_16x16x32_bf16(Vh1, GL1, q, 0, 0, 0);
        p = __builtin_amdgcn_mfma_f32_16x16x32_bf16(Vh0, GH0, p, 0, 0, 0);
        q = __builtin_amdgcn_mfma_f32_16x16x32_bf16(Vh1, GH1, q, 0, 0, 0);
        f32x4 o = p + q;

        __builtin_nontemporal_store(o, (f32x4*)(out + (size_t)e_cur * 16 + 4 * g));

        // ---- rotate pipeline state ----
        e_cur = e_nxt;
        x0 = n0; x1 = n1; x2 = n2; x3 = n3;
        e_nxt = e_nn; ri_n = ri_nn; si_n = si_nn; gi_n = gi_nn;
    }
    #undef TILE_OF
}

extern "C" void kernel_launch(void* const* d_in, const int* in_sizes, int n_in,
                              void* d_out, int out_size, void* d_ws, size_t ws_size,
                              hipStream_t stream) {
    const float* edges    = (const float*)d_in[0];
    const float* nodes    = (const float*)d_in[1];
    const float* globals_ = (const float*)d_in[2];
    const float* W0 = (const float*)d_in[3];
    const float* b0 = (const float*)d_in[4];
    const float* W1 = (const float*)d_in[5];
    const float* b1 = (const float*)d_in[6];
    const float* W2 = (const float*)d_in[7];
    const float* b2 = (const float*)d_in[8];
    const int* senders   = (const int*)d_in[9];
    const int* receivers = (const int*)d_in[10];
    const int* gids      = (const int*)d_in[11];
    float* out = (float*)d_out;

    const int n_edges = in_sizes[9];          // 1,600,000
    const int n_tiles = n_edges >> 4;         // 16-edge wave tiles

    prep_kernel<<<72, 256, 0, stream>>>(W0, b0, W1, b1, W2, b2, d_ws);

    int grid = 768;                           // persistent: 3 blocks/CU (LDS 46 KB)
    if (grid > (n_tiles + 3) / 4) grid = (n_tiles + 3) / 4;
    const int waves = grid * 4;
    const int iters = (n_tiles + waves - 1) / waves;
    edge_mlp_kernel<<<grid, 256, 0, stream>>>(edges, nodes, globals_, senders, receivers,
                                              gids, d_ws, out, n_tiles, iters);
}

// Round 4
// 270.187 us; speedup vs baseline: 1.9177x; 1.9177x over previous
//
#include <hip/hip_runtime.h>
#include <hip/hip_bf16.h>

// EdgeBlock: out[e] = (relu(relu(x@W0+b0)@W1+b1))@W2+b2, x = [edge|recv|send|glob] (64)
// bf16 hi/lo split MFMA (fp32-equivalent accuracy), transposed products so inter-layer
// data stays lane-local. R4: LDS weights kept, but (1) sched_barrier(0) fences stop the
// compiler hoisting all weight ds_reads (R3's spill storm: FETCH 173MB->1.2GB), (2) compact
// biases shrink LDS 46->37.4KB (4 blocks/CU), (3) launch_bounds(256,4) -> 128-reg cap,
// 16 waves/CU target.

typedef float f32x4 __attribute__((ext_vector_type(4)));
typedef short short8 __attribute__((ext_vector_type(8)));
typedef unsigned int u32;
typedef unsigned int u32x4 __attribute__((ext_vector_type(4)));

__device__ __forceinline__ unsigned short f2bf(float f) {
    union { float f; u32 u; } v; v.f = f;
    u32 u = v.u;
    u += 0x7FFFu + ((u >> 16) & 1u);   // RNE
    return (unsigned short)(u >> 16);
}
__device__ __forceinline__ float bf2f(unsigned short b) {
    union { u32 u; float f; } v; v.u = ((u32)b) << 16;
    return v.f;
}
// packed pair: low half = bf16(a), high half = bf16(b)   (v_cvt_pk_bf16_f32)
__device__ __forceinline__ u32 pk2(float a, float b) {
    union { __hip_bfloat162 v; u32 u; } c;
    c.v = __float22bfloat162_rn(make_float2(a, b));
    return c.u;
}
__device__ __forceinline__ float lo_f(u32 p) { union { u32 u; float f; } c; c.u = p << 16; return c.f; }
__device__ __forceinline__ float hi_f(u32 p) { union { u32 u; float f; } c; c.u = p & 0xffff0000u; return c.f; }
__device__ __forceinline__ void split4(f32x4 v, u32& h0, u32& h1, u32& l0, u32& l1) {
    h0 = pk2(v[0], v[1]);
    h1 = pk2(v[2], v[3]);
    l0 = pk2(v[0] - lo_f(h0), v[1] - hi_f(h0));
    l1 = pk2(v[2] - lo_f(h1), v[3] - hi_f(h1));
}
__device__ __forceinline__ short8 s8(u32 a, u32 b, u32 c, u32 d) {
    union { u32x4 u; short8 s; } t; t.u = u32x4{a, b, c, d}; return t.s;
}

// ---------------- prep: pack weights into MFMA fragment layout in ws -------------
// ws layout: ushort w0h[4096] w0l[4096] w1h[4096] w1l[4096] w2h[1024] w2l[1024]
// then (float, byte 36864): b0[64] b1[64] b2[16]  (compact)   total 37440 B
__global__ void prep_kernel(const float* __restrict__ W0, const float* __restrict__ b0,
                            const float* __restrict__ W1, const float* __restrict__ b1,
                            const float* __restrict__ W2, const float* __restrict__ b2,
                            void* __restrict__ ws) {
    unsigned short* w0h = (unsigned short*)ws;
    unsigned short* w0l = w0h + 4096;
    unsigned short* w1h = w0h + 8192;
    unsigned short* w1l = w0h + 12288;
    unsigned short* w2h = w0h + 16384;
    unsigned short* w2l = w0h + 17408;
    float* bc = (float*)(w0h + 18432);
    const int tid = blockIdx.x * blockDim.x + threadIdx.x;
    const int gstride = gridDim.x * blockDim.x;

    // W0 frags: A[m=hid][k=in] = W0[k][m]; k-slot map mu0 = 32*kt + 8*g + j
    for (int idx = tid; idx < 4096; idx += gstride) {
        int j = idx & 7, lane = (idx >> 3) & 63, f = idx >> 9;
        int t = f >> 1, kt = f & 1, mr = lane & 15, g = lane >> 4;
        float w = W0[(32 * kt + 8 * g + j) * 64 + (16 * t + mr)];
        unsigned short h = f2bf(w);
        w0h[idx] = h;
        w0l[idx] = f2bf(w - bf2f(h));
    }
    // W1 frags: k-slot map mu = 16*(2*kt + (j>>2)) + 4*g + (j&3)  (matches layer-0 output)
    for (int idx = tid; idx < 4096; idx += gstride) {
        int j = idx & 7, lane = (idx >> 3) & 63, f = idx >> 9;
        int t = f >> 1, kt = f & 1, mr = lane & 15, g = lane >> 4;
        int mu = 16 * (2 * kt + (j >> 2)) + 4 * g + (j & 3);
        float w = W1[mu * 64 + (16 * t + mr)];
        unsigned short h = f2bf(w);
        w1h[idx] = h;
        w1l[idx] = f2bf(w - bf2f(h));
    }
    // W2 frags: [2][64][8], same mu map, single M-tile
    for (int idx = tid; idx < 1024; idx += gstride) {
        int j = idx & 7, lane = (idx >> 3) & 63, kt = idx >> 9;
        int mr = lane & 15, g = lane >> 4;
        int mu = 16 * (2 * kt + (j >> 2)) + 4 * g + (j & 3);
        float w = W2[mu * 16 + mr];
        unsigned short h = f2bf(w);
        w2h[idx] = h;
        w2l[idx] = f2bf(w - bf2f(h));
    }
    // compact biases (identity copy; lane indexes them directly)
    for (int idx = tid; idx < 64; idx += gstride) { bc[idx] = b0[idx]; bc[64 + idx] = b1[idx]; }
    for (int idx = tid; idx < 16; idx += gstride) bc[128 + idx] = b2[idx];
}

// ---------------- main kernel: one wave computes 16 edges per iteration ----------------
__global__ __launch_bounds__(256, 4) void edge_mlp_kernel(
    const float* __restrict__ edges, const float* __restrict__ nodes,
    const float* __restrict__ globals_, const int* __restrict__ senders,
    const int* __restrict__ receivers, const int* __restrict__ gids,
    const void* __restrict__ ws, float* __restrict__ out, int n_tiles, int iters) {

    __shared__ __align__(16) float smem[9360];    // 37440 B: weight frags + compact biases
    {
        const f32x4* src = (const f32x4*)ws;
        f32x4* dst = (f32x4*)smem;
        for (int i = threadIdx.x; i < 2340; i += 256) dst[i] = src[i];
    }
    __syncthreads();

    const short8* w0h = (const short8*)smem;              // [8][64] frags
    const short8* w0l = w0h + 512;
    const short8* w1h = w0h + 1024;
    const short8* w1l = w0h + 1536;
    const short8* w2h = w0h + 2048;                       // [2][64]
    const short8* w2l = w0h + 2176;
    const float* bia = smem + 9216;                       // b0[64] b1[64] b2[16]

    const int lane = threadIdx.x & 63;
    const int wv = threadIdx.x >> 6;
    const int mr = lane & 15;
    const int g = lane >> 4;

    const int W = gridDim.x << 2;
    const int wave_id = (blockIdx.x << 2) | wv;
    const int last = n_tiles - 1;
    #define TILE_OF(i) (((wave_id + (i) * W) < n_tiles) ? (wave_id + (i) * W) : last)

    // ---- pipeline prologue ----
    int e_cur = TILE_OF(0) * 16 + mr;
    int ri0 = receivers[e_cur], si0 = senders[e_cur], gi0 = gids[e_cur];
    const float* p0 = (g < 2) ? (edges + (size_t)e_cur * 16 + 8 * g)
                              : (nodes + (size_t)ri0 * 16 + 8 * (g - 2));
    const float* p1 = (g < 2) ? (nodes + (size_t)si0 * 16 + 8 * g)
                              : (globals_ + (size_t)gi0 * 16 + 8 * (g - 2));
    f32x4 x0 = *(const f32x4*)p0;
    f32x4 x1 = *(const f32x4*)(p0 + 4);
    f32x4 x2 = *(const f32x4*)p1;
    f32x4 x3 = *(const f32x4*)(p1 + 4);

    int e_nxt = TILE_OF(1) * 16 + mr;
    int ri_n = receivers[e_nxt], si_n = senders[e_nxt], gi_n = gids[e_nxt];

    for (int i = 0; i < iters; ++i) {
        // ---- prefetch data for iteration i+1 (loads stay in flight across sched fences) ----
        const float* q0 = (g < 2) ? (edges + (size_t)e_nxt * 16 + 8 * g)
                                  : (nodes + (size_t)ri_n * 16 + 8 * (g - 2));
        const float* q1 = (g < 2) ? (nodes + (size_t)si_n * 16 + 8 * g)
                                  : (globals_ + (size_t)gi_n * 16 + 8 * (g - 2));
        f32x4 n0 = *(const f32x4*)q0;
        f32x4 n1 = *(const f32x4*)(q0 + 4);
        f32x4 n2 = *(const f32x4*)q1;
        f32x4 n3 = *(const f32x4*)(q1 + 4);

        // ---- prefetch indices for iteration i+2 ----
        int e_nn = TILE_OF(i + 2) * 16 + mr;
        int ri_nn = receivers[e_nn], si_nn = senders[e_nn], gi_nn = gids[e_nn];

        // ---- split inputs (k-slot map mu0 = 32*kt + 8*g + j; pairs contiguous) ----
        u32 ah0, ah1, al0, al1, bh0, bh1, bl0, bl1;
        u32 ch0, ch1, cl0, cl1, dh0, dh1, dl0, dl1;
        split4(x0, ah0, ah1, al0, al1);
        split4(x1, bh0, bh1, bl0, bl1);
        split4(x2, ch0, ch1, cl0, cl1);
        split4(x3, dh0, dh1, dl0, dl1);
        short8 XH0 = s8(ah0, ah1, bh0, bh1), XL0 = s8(al0, al1, bl0, bl1);
        short8 XH1 = s8(ch0, ch1, dh0, dh1), XL1 = s8(cl0, cl1, dl0, dl1);

        // ---- layer 0 (hi/lo: Wl*Xh + Wh*Xl + Wh*Xh), bias in C-init, 2 acc chains ----
        u32 HHw[2][4], HLw[2][4];
#pragma unroll
        for (int t = 0; t < 4; ++t) {
            short8 Wh0 = w0h[(t * 2 + 0) * 64 + lane];
            short8 Wh1 = w0h[(t * 2 + 1) * 64 + lane];
            short8 Wl0 = w0l[(t * 2 + 0) * 64 + lane];
            short8 Wl1 = w0l[(t * 2 + 1) * 64 + lane];
            f32x4 p = *(const f32x4*)(bia + 16 * t + 4 * g);
            f32x4 q = {0.f, 0.f, 0.f, 0.f};
            p = __builtin_amdgcn_mfma_f32_16x16x32_bf16(Wl0, XH0, p, 0, 0, 0);
            q = __builtin_amdgcn_mfma_f32_16x16x32_bf16(Wl1, XH1, q, 0, 0, 0);
            p = __builtin_amdgcn_mfma_f32_16x16x32_bf16(Wh0, XL0, p, 0, 0, 0);
            q = __builtin_amdgcn_mfma_f32_16x16x32_bf16(Wh1, XL1, q, 0, 0, 0);
            p = __builtin_amdgcn_mfma_f32_16x16x32_bf16(Wh0, XH0, p, 0, 0, 0);
            q = __builtin_amdgcn_mfma_f32_16x16x32_bf16(Wh1, XH1, q, 0, 0, 0);
            f32x4 s = p + q;
            float v0 = fmaxf(s[0], 0.f), v1 = fmaxf(s[1], 0.f);
            float v2 = fmaxf(s[2], 0.f), v3 = fmaxf(s[3], 0.f);
            u32 h0 = pk2(v0, v1), h1 = pk2(v2, v3);
            u32 l0 = pk2(v0 - lo_f(h0), v1 - hi_f(h0));
            u32 l1 = pk2(v2 - lo_f(h1), v3 - hi_f(h1));
            int kt = t >> 1, sl = (t & 1) << 1;
            HHw[kt][sl] = h0; HHw[kt][sl + 1] = h1;
            HLw[kt][sl] = l0; HLw[kt][sl + 1] = l1;
            if (t == 1) __builtin_amdgcn_sched_barrier(0);   // fence: cap live weight frags
        }
        __builtin_amdgcn_sched_barrier(0);
        short8 HH0 = s8(HHw[0][0], HHw[0][1], HHw[0][2], HHw[0][3]);
        short8 HH1 = s8(HHw[1][0], HHw[1][1], HHw[1][2], HHw[1][3]);
        short8 HL0 = s8(HLw[0][0], HLw[0][1], HLw[0][2], HLw[0][3]);
        short8 HL1 = s8(HLw[1][0], HLw[1][1], HLw[1][2], HLw[1][3]);

        // ---- layer 1 ----
        u32 GHw[2][4], GLw[2][4];
#pragma unroll
        for (int t = 0; t < 4; ++t) {
            short8 Wh0 = w1h[(t * 2 + 0) * 64 + lane];
            short8 Wh1 = w1h[(t * 2 + 1) * 64 + lane];
            short8 Wl0 = w1l[(t * 2 + 0) * 64 + lane];
            short8 Wl1 = w1l[(t * 2 + 1) * 64 + lane];
            f32x4 p = *(const f32x4*)(bia + 64 + 16 * t + 4 * g);
            f32x4 q = {0.f, 0.f, 0.f, 0.f};
            p = __builtin_amdgcn_mfma_f32_16x16x32_bf16(Wl0, HH0, p, 0, 0, 0);
            q = __builtin_amdgcn_mfma_f32_16x16x32_bf16(Wl1, HH1, q, 0, 0, 0);
            p = __builtin_amdgcn_mfma_f32_16x16x32_bf16(Wh0, HL0, p, 0, 0, 0);
            q = __builtin_amdgcn_mfma_f32_16x16x32_bf16(Wh1, HL1, q, 0, 0, 0);
            p = __builtin_amdgcn_mfma_f32_16x16x32_bf16(Wh0, HH0, p, 0, 0, 0);
            q = __builtin_amdgcn_mfma_f32_16x16x32_bf16(Wh1, HH1, q, 0, 0, 0);
            f32x4 s = p + q;
            float v0 = fmaxf(s[0], 0.f), v1 = fmaxf(s[1], 0.f);
            float v2 = fmaxf(s[2], 0.f), v3 = fmaxf(s[3], 0.f);
            u32 h0 = pk2(v0, v1), h1 = pk2(v2, v3);
            u32 l0 = pk2(v0 - lo_f(h0), v1 - hi_f(h0));
            u32 l1 = pk2(v2 - lo_f(h1), v3 - hi_f(h1));
            int kt = t >> 1, sl = (t & 1) << 1;
            GHw[kt][sl] = h0; GHw[kt][sl + 1] = h1;
            GLw[kt][sl] = l0; GLw[kt][sl + 1] = l1;
            if (t == 1) __builtin_amdgcn_sched_barrier(0);
        }
        __builtin_amdgcn_sched_barrier(0);
        short8 GH0 = s8(GHw[0][0], GHw[0][1], GHw[0][2], GHw[0][3]);
        short8 GH1 = s8(GHw[1][0], GHw[1][1], GHw[1][2], GHw[1][3]);
        short8 GL0 = s8(GLw[0][0], GLw[0][1], GLw[0][2], GLw[0][3]);
        short8 GL1 = s8(GLw[1][0], GLw[1][1], GLw[1][2], GLw[1][3]);

        // ---- layer 2 (single M-tile) ----
        short8 Vh0 = w2h[lane], Vh1 = w2h[64 + lane];
        short8 Vl0 = w2l[lane], Vl1 = w2l[64 + lane];
        f32x4 p = *(const f32x4*)(bia + 128 + 4 * g);
        f32x4 q = {0.f, 0.f, 0.f, 0.f};
        p = __builtin_amdgcn_mfma_f32_16x16x32_bf16(Vl0, GH0, p, 0, 0, 0);
        q = __builtin_amdgcn_mfma_f32_16x16x32_bf16(Vl1, GH1, q, 0, 0, 0);
        p = __builtin_amdgcn_mfma_f32_16x16x32_bf16(Vh0, GL0, p, 0, 0, 0);
        q = __builtin_amdgcn_mfma_f32_16x16x32_bf16(Vh1, GL1, q, 0, 0, 0);
        p = __builtin_amdgcn_mfma_f32_16x16x32_bf16(Vh0, GH0, p, 0, 0, 0);
        q = __builtin_amdgcn_mfma_f32_16x16x32_bf16(Vh1, GH1, q, 0, 0, 0);
        f32x4 o = p + q;

        __builtin_nontemporal_store(o, (f32x4*)(out + (size_t)e_cur * 16 + 4 * g));

        // ---- rotate pipeline state ----
        e_cur = e_nxt;
        x0 = n0; x1 = n1; x2 = n2; x3 = n3;
        e_nxt = e_nn; ri_n = ri_nn; si_n = si_nn; gi_n = gi_nn;
    }
    #undef TILE_OF
}

extern "C" void kernel_launch(void* const* d_in, const int* in_sizes, int n_in,
                              void* d_out, int out_size, void* d_ws, size_t ws_size,
                              hipStream_t stream) {
    const float* edges    = (const float*)d_in[0];
    const float* nodes    = (const float*)d_in[1];
    const float* globals_ = (const float*)d_in[2];
    const float* W0 = (const float*)d_in[3];
    const float* b0 = (const float*)d_in[4];
    const float* W1 = (const float*)d_in[5];
    const float* b1 = (const float*)d_in[6];
    const float* W2 = (const float*)d_in[7];
    const float* b2 = (const float*)d_in[8];
    const int* senders   = (const int*)d_in[9];
    const int* receivers = (const int*)d_in[10];
    const int* gids      = (const int*)d_in[11];
    float* out = (float*)d_out;

    const int n_edges = in_sizes[9];          // 1,600,000
    const int n_tiles = n_edges >> 4;         // 16-edge wave tiles

    prep_kernel<<<72, 256, 0, stream>>>(W0, b0, W1, b1, W2, b2, d_ws);

    int grid = 1024;                          // persistent: 4 blocks/CU (LDS 37.4 KB)
    if (grid > (n_tiles + 3) / 4) grid = (n_tiles + 3) / 4;
    const int waves = grid * 4;
    const int iters = (n_tiles + waves - 1) / waves;
    edge_mlp_kernel<<<grid, 256, 0, stream>>>(edges, nodes, globals_, senders, receivers,
                                              gids, d_ws, out, n_tiles, iters);
}